// Round 8
// baseline (137.880 us; speedup 1.0000x reference)
//
#include <hip/hip_runtime.h>
#include <cstdint>

#define T_SEQ 4096
#define E_DIM 1024
#define N_B   8
#define BT    16       // tokens per block
typedef float v2f __attribute__((ext_vector_type(2)));

constexpr int LW[4] = {2, 8, 12, 6};

// dec_lo
constexpr float DLf[4][12] = {
  {0.7071067811865476f, 0.7071067811865476f, 0,0,0,0,0,0,0,0,0,0},
  {-0.010597401784997278f, 0.032883011666982945f, 0.030841381835986965f, -0.18703481171888114f,
   -0.02798376941698385f, 0.6308807679295904f, 0.7148465705525415f, 0.23037781330885523f, 0,0,0,0},
  {-0.007800708325034148f, 0.0017677118642428036f, 0.04472490177066578f, -0.021060292512300564f,
   -0.07263752278646252f, 0.3379294217276218f, 0.787641141030194f, 0.4910559419267466f,
   -0.048311742585633f, -0.11799011114819057f, 0.0034907120842174702f, 0.015404109327027373f},
  {-0.08838834764831845f, 0.08838834764831845f, 0.7071067811865476f, 0.7071067811865476f,
    0.08838834764831845f, -0.08838834764831845f, 0,0,0,0,0,0},
};
// dec_hi
constexpr float DHf[4][12] = {
  {-0.7071067811865476f, 0.7071067811865476f, 0,0,0,0,0,0,0,0,0,0},
  {-0.23037781330885523f, 0.7148465705525415f, -0.6308807679295904f, -0.02798376941698385f,
    0.18703481171888114f, 0.030841381835986965f, -0.032883011666982945f, -0.010597401784997278f, 0,0,0,0},
  {-0.015404109327027373f, 0.0034907120842174702f, 0.11799011114819057f, -0.048311742585633f,
   -0.4910559419267466f, 0.787641141030194f, -0.3379294217276218f, -0.07263752278646252f,
    0.021060292512300564f, 0.04472490177066578f, -0.0017677118642428036f, -0.007800708325034148f},
  {0,0,-0.7071067811865476f, 0.7071067811865476f, 0,0, 0,0,0,0,0,0},
};
// rec_lo
constexpr float RLf[4][12] = {
  {0.7071067811865476f, 0.7071067811865476f, 0,0,0,0,0,0,0,0,0,0},
  {0.23037781330885523f, 0.7148465705525415f, 0.6308807679295904f, -0.02798376941698385f,
   -0.18703481171888114f, 0.030841381835986965f, 0.032883011666982945f, -0.010597401784997278f, 0,0,0,0},
  {0.015404109327027373f, 0.0034907120842174702f, -0.11799011114819057f, -0.048311742585633f,
   0.4910559419267466f, 0.787641141030194f, 0.3379294217276218f, -0.07263752278646252f,
   -0.021060292512300564f, 0.04472490177066578f, 0.0017677118642428036f, -0.007800708325034148f},
  {0,0,0.7071067811865476f, 0.7071067811865476f, 0,0, 0,0,0,0,0,0},
};
// rec_hi
constexpr float RHf[4][12] = {
  {0.7071067811865476f, -0.7071067811865476f, 0,0,0,0,0,0,0,0,0,0},
  {-0.010597401784997278f, -0.032883011666982945f, 0.030841381835986965f, 0.18703481171888114f,
   -0.02798376941698385f, -0.6308807679295904f, 0.7148465705525415f, -0.23037781330885523f, 0,0,0,0},
  {-0.007800708325034148f, -0.0017677118642428036f, 0.04472490177066578f, 0.021060292512300564f,
   -0.07263752278646252f, -0.3379294217276218f, 0.787641141030194f, -0.4910559419267466f,
   -0.048311742585633f, 0.11799011114819057f, 0.0034907120842174702f, -0.015404109327027373f},
  {-0.08838834764831845f, -0.08838834764831845f, 0.7071067811865476f, -0.7071067811865476f,
    0.08838834764831845f, 0.08838834764831845f, 0,0,0,0,0,0},
};

__device__ __forceinline__ v2f sv(float c) { return v2f{c, c}; }

template <int W, int KK>
__device__ __forceinline__ void step(const v2f (&xw)[36], v2f (&acc)[16],
                                     const v2f la, const v2f ld, const v2f gw) {
  constexpr int L = LW[W];
  if constexpr (KK < L / 2 + 7) {
    v2f lo = {0.f, 0.f}, hi = {0.f, 0.f};
#pragma unroll
    for (int m = 0; m < L; ++m) {
      const v2f xv = xw[2 * KK + 11 - m];
      if (DLf[W][m] != 0.0f) lo += sv(DLf[W][m]) * xv;
      if (DHf[W][m] != 0.0f) hi += sv(DHf[W][m]) * xv;
    }
    v2f cl, ch;
    cl.x = __builtin_amdgcn_fmed3f(lo.x, -la.x, la.x);
    cl.y = __builtin_amdgcn_fmed3f(lo.y, -la.y, la.y);
    ch.x = __builtin_amdgcn_fmed3f(hi.x, -ld.x, ld.x);
    ch.y = __builtin_amdgcn_fmed3f(hi.y, -ld.y, ld.y);
    const v2f loS = (lo - cl) * gw;
    const v2f hiS = (hi - ch) * gw;
#pragma unroll
    for (int m = 0; m < L; ++m) {
      const int j = 2 * KK + m + 2 - L;   // compile-time after unroll
      if (j >= 0 && j < 16) {
        if (RLf[W][m] != 0.0f) acc[j] += loS * sv(RLf[W][m]);
        if (RHf[W][m] != 0.0f) acc[j] += hiS * sv(RHf[W][m]);
      }
    }
  }
}

template <int KK>
__device__ __forceinline__ void sweep(const v2f (&xw)[36], v2f (&acc)[16],
                                      const v2f la, const v2f ld,
                                      const v2f gw0, const v2f gw1,
                                      const v2f gw2, const v2f gw3) {
  if constexpr (KK < 13) {
    step<0, KK>(xw, acc, la, ld, gw0);
    step<1, KK>(xw, acc, la, ld, gw1);
    step<2, KK>(xw, acc, la, ld, gw2);
    step<3, KK>(xw, acc, la, ld, gw3);
    if constexpr (KK < 8) {
      acc[2 * KK]     += xw[2 * KK + 10];   // residual y = x + sum w_i rec_i
      acc[2 * KK + 1] += xw[2 * KK + 11];
    }
    sweep<KK + 1>(xw, acc, la, ld, gw0, gw1, gw2, gw3);
  }
}

// Fused wavelet + LayerNorm. Block = 512 threads = all 1024 channels (2/thread)
// x 16 tokens. Per-thread wavelet work identical to the R7 kernel; LN is a
// block-internal reduction over channels, eliminating the second kernel's
// 256MB L3 round trip.
__global__ __launch_bounds__(512) void wlm_fused(
    const float* __restrict__ x,
    const float* __restrict__ la_, const float* __restrict__ ld_,
    const float* __restrict__ lg_, const float* __restrict__ th_,
    const float* __restrict__ bl_,
    const float* __restrict__ lnw, const float* __restrict__ lnb,
    float* __restrict__ y) {
  __shared__ float ps[BT][8], pq[BT][8], stat[BT][2];

  const int tid  = threadIdx.x;          // 0..511
  const int lane = tid & 63;
  const int wave = tid >> 6;             // 0..7
  const int e  = 2 * tid;                // channel pair (e, e+1)
  const int b  = blockIdx.z;
  const int sA = blockIdx.x * BT;        // this block's 16 tokens

  // ---- window: x_ref[sA-10 .. sA+25] for channel pair (e, e+1) ----
  const size_t rowb = (size_t)b * T_SEQ;
  v2f xw[36];
  if (sA >= 10 && sA + 26 <= T_SEQ) {
    const float* p = &x[(rowb + sA - 10) * E_DIM + e];
#pragma unroll
    for (int i = 0; i < 36; ++i) {
      xw[i] = *reinterpret_cast<const v2f*>(p + (size_t)i * E_DIM);
    }
  } else {
#pragma unroll
    for (int i = 0; i < 36; ++i) {
      int g = sA - 10 + i;
      g = (g < 0) ? -g : g;
      g = (g >= T_SEQ) ? (2 * T_SEQ - 2 - g) : g;
      xw[i] = *reinterpret_cast<const v2f*>(&x[(rowb + g) * E_DIM + e]);
    }
  }

  // ---- per-channel-pair params ----
  const v2f la = *reinterpret_cast<const v2f*>(&la_[e]);
  const v2f ld = *reinterpret_cast<const v2f*>(&ld_[e]);
  const v2f lg = *reinterpret_cast<const v2f*>(&lg_[e]);
  const v2f th = *reinterpret_cast<const v2f*>(&th_[e]);
  v2f g2;
  g2.x = (fmaxf(lg.x, 0.f) + log1pf(expf(-fabsf(lg.x))) + 1e-6f) * cosf(th.x);
  g2.y = (fmaxf(lg.y, 0.f) + log1pf(expf(-fabsf(lg.y))) + 1e-6f) * cosf(th.y);

  const float b0 = bl_[0], b1 = bl_[1], b2 = bl_[2], b3 = bl_[3];
  const float mx = fmaxf(fmaxf(b0, b1), fmaxf(b2, b3));
  const float w0 = expf(b0 - mx), w1 = expf(b1 - mx),
              w2 = expf(b2 - mx), w3 = expf(b3 - mx);
  const float wr = 1.f / (w0 + w1 + w2 + w3);
  const v2f gw0 = g2 * sv(w0 * wr), gw1 = g2 * sv(w1 * wr),
            gw2 = g2 * sv(w2 * wr), gw3 = g2 * sv(w3 * wr);

  v2f acc[16];
#pragma unroll
  for (int j = 0; j < 16; ++j) acc[j] = v2f{0.f, 0.f};

  sweep<0>(xw, acc, la, ld, gw0, gw1, gw2, gw3);
  // acc[j] now holds pre-LN y for token sA+j, channels (e, e+1)

  // ---- LN stats: per token, reduce over 1024 channels ----
#pragma unroll
  for (int j = 0; j < BT; ++j) {
    float s = acc[j].x + acc[j].y;
    float q = acc[j].x * acc[j].x + acc[j].y * acc[j].y;
#pragma unroll
    for (int off = 32; off; off >>= 1) {
      s += __shfl_down(s, off);
      q += __shfl_down(q, off);
    }
    if (lane == 0) { ps[j][wave] = s; pq[j][wave] = q; }
  }
  __syncthreads();
  if (tid < BT) {
    float S = 0.f, Q = 0.f;
#pragma unroll
    for (int w = 0; w < 8; ++w) { S += ps[tid][w]; Q += pq[tid][w]; }
    const float mu = S * (1.f / E_DIM);
    const float var = Q * (1.f / E_DIM) - mu * mu;
    stat[tid][0] = mu;
    stat[tid][1] = rsqrtf(var + 1e-5f);
  }
  __syncthreads();

  // ---- normalize + affine + store ----
  const v2f wv = *reinterpret_cast<const v2f*>(&lnw[e]);
  const v2f bv = *reinterpret_cast<const v2f*>(&lnb[e]);
#pragma unroll
  for (int j = 0; j < BT; ++j) {
    const float mu = stat[j][0], rs = stat[j][1];
    const v2f o = (acc[j] - sv(mu)) * sv(rs) * wv + bv;
    *reinterpret_cast<v2f*>(&y[(rowb + sA + j) * E_DIM + e]) = o;
  }
}

extern "C" void kernel_launch(void* const* d_in, const int* in_sizes, int n_in,
                              void* d_out, int out_size, void* d_ws, size_t ws_size,
                              hipStream_t stream) {
  const float* x   = (const float*)d_in[0];
  const float* la  = (const float*)d_in[1];
  const float* ldt = (const float*)d_in[2];
  const float* lg  = (const float*)d_in[3];
  const float* th  = (const float*)d_in[4];
  const float* bl  = (const float*)d_in[5];
  const float* lnw = (const float*)d_in[6];
  const float* lnb = (const float*)d_in[7];
  float* out = (float*)d_out;

  dim3 g(T_SEQ / BT, 1, N_B);  // (256, 1, 8)
  wlm_fused<<<g, 512, 0, stream>>>(x, la, ldt, lg, th, bl, lnw, lnb, out);
}

// Round 9
// 111.034 us; speedup vs baseline: 1.2418x; 1.2418x over previous
//
#include <hip/hip_runtime.h>
#include <cstdint>

#define T_SEQ 4096
#define E_DIM 1024
#define N_B   8
#define SC    128      // seq positions per block
#define TILE_P 148     // s0-10 .. s0+137 (37 groups of 4 rows)
typedef float v2f __attribute__((ext_vector_type(2)));

constexpr int LW[4] = {2, 8, 12, 6};

// dec_lo
constexpr float DLf[4][12] = {
  {0.7071067811865476f, 0.7071067811865476f, 0,0,0,0,0,0,0,0,0,0},
  {-0.010597401784997278f, 0.032883011666982945f, 0.030841381835986965f, -0.18703481171888114f,
   -0.02798376941698385f, 0.6308807679295904f, 0.7148465705525415f, 0.23037781330885523f, 0,0,0,0},
  {-0.007800708325034148f, 0.0017677118642428036f, 0.04472490177066578f, -0.021060292512300564f,
   -0.07263752278646252f, 0.3379294217276218f, 0.787641141030194f, 0.4910559419267466f,
   -0.048311742585633f, -0.11799011114819057f, 0.0034907120842174702f, 0.015404109327027373f},
  {-0.08838834764831845f, 0.08838834764831845f, 0.7071067811865476f, 0.7071067811865476f,
    0.08838834764831845f, -0.08838834764831845f, 0,0,0,0,0,0},
};
// dec_hi
constexpr float DHf[4][12] = {
  {-0.7071067811865476f, 0.7071067811865476f, 0,0,0,0,0,0,0,0,0,0},
  {-0.23037781330885523f, 0.7148465705525415f, -0.6308807679295904f, -0.02798376941698385f,
    0.18703481171888114f, 0.030841381835986965f, -0.032883011666982945f, -0.010597401784997278f, 0,0,0,0},
  {-0.015404109327027373f, 0.0034907120842174702f, 0.11799011114819057f, -0.048311742585633f,
   -0.4910559419267466f, 0.787641141030194f, -0.3379294217276218f, -0.07263752278646252f,
    0.021060292512300564f, 0.04472490177066578f, -0.0017677118642428036f, -0.007800708325034148f},
  {0,0,-0.7071067811865476f, 0.7071067811865476f, 0,0, 0,0,0,0,0,0},
};
// rec_lo
constexpr float RLf[4][12] = {
  {0.7071067811865476f, 0.7071067811865476f, 0,0,0,0,0,0,0,0,0,0},
  {0.23037781330885523f, 0.7148465705525415f, 0.6308807679295904f, -0.02798376941698385f,
   -0.18703481171888114f, 0.030841381835986965f, 0.032883011666982945f, -0.010597401784997278f, 0,0,0,0},
  {0.015404109327027373f, 0.0034907120842174702f, -0.11799011114819057f, -0.048311742585633f,
   0.4910559419267466f, 0.787641141030194f, 0.3379294217276218f, -0.07263752278646252f,
   -0.021060292512300564f, 0.04472490177066578f, 0.0017677118642428036f, -0.007800708325034148f},
  {0,0,0.7071067811865476f, 0.7071067811865476f, 0,0, 0,0,0,0,0,0},
};
// rec_hi
constexpr float RHf[4][12] = {
  {0.7071067811865476f, -0.7071067811865476f, 0,0,0,0,0,0,0,0,0,0},
  {-0.010597401784997278f, -0.032883011666982945f, 0.030841381835986965f, 0.18703481171888114f,
   -0.02798376941698385f, -0.6308807679295904f, 0.7148465705525415f, -0.23037781330885523f, 0,0,0,0},
  {-0.007800708325034148f, -0.0017677118642428036f, 0.04472490177066578f, 0.021060292512300564f,
   -0.07263752278646252f, -0.3379294217276218f, 0.787641141030194f, -0.4910559419267466f,
   -0.048311742585633f, 0.11799011114819057f, 0.0034907120842174702f, -0.015404109327027373f},
  {-0.08838834764831845f, -0.08838834764831845f, 0.7071067811865476f, -0.7071067811865476f,
    0.08838834764831845f, 0.08838834764831845f, 0,0,0,0,0,0},
};

__device__ __forceinline__ v2f sv(float c) { return v2f{c, c}; }

template <int W, int KK>
__device__ __forceinline__ void step(const v2f (&xw)[36], v2f (&acc)[16],
                                     const v2f la, const v2f ld, const v2f gw) {
  constexpr int L = LW[W];
  if constexpr (KK < L / 2 + 7) {
    v2f lo = {0.f, 0.f}, hi = {0.f, 0.f};
#pragma unroll
    for (int m = 0; m < L; ++m) {
      const v2f xv = xw[2 * KK + 11 - m];
      if (DLf[W][m] != 0.0f) lo += sv(DLf[W][m]) * xv;
      if (DHf[W][m] != 0.0f) hi += sv(DHf[W][m]) * xv;
    }
    v2f cl, ch;
    cl.x = __builtin_amdgcn_fmed3f(lo.x, -la.x, la.x);
    cl.y = __builtin_amdgcn_fmed3f(lo.y, -la.y, la.y);
    ch.x = __builtin_amdgcn_fmed3f(hi.x, -ld.x, ld.x);
    ch.y = __builtin_amdgcn_fmed3f(hi.y, -ld.y, ld.y);
    const v2f loS = (lo - cl) * gw;
    const v2f hiS = (hi - ch) * gw;
#pragma unroll
    for (int m = 0; m < L; ++m) {
      const int j = 2 * KK + m + 2 - L;   // compile-time after unroll
      if (j >= 0 && j < 16) {
        if (RLf[W][m] != 0.0f) acc[j] += loS * sv(RLf[W][m]);
        if (RHf[W][m] != 0.0f) acc[j] += hiS * sv(RHf[W][m]);
      }
    }
  }
}

template <int KK>
__device__ __forceinline__ void sweep(const v2f (&xw)[36], v2f (&acc)[16],
                                      const v2f la, const v2f ld,
                                      const v2f gw0, const v2f gw1,
                                      const v2f gw2, const v2f gw3) {
  if constexpr (KK < 13) {
    step<0, KK>(xw, acc, la, ld, gw0);
    step<1, KK>(xw, acc, la, ld, gw1);
    step<2, KK>(xw, acc, la, ld, gw2);
    step<3, KK>(xw, acc, la, ld, gw3);
    if constexpr (KK < 8) {
      acc[2 * KK]     += xw[2 * KK + 10];   // residual y = x + sum w_i rec_i
      acc[2 * KK + 1] += xw[2 * KK + 11];
    }
    sweep<KK + 1>(xw, acc, la, ld, gw0, gw1, gw2, gw3);
  }
}

__device__ __forceinline__ void gload_lds16(const float* gsrc, float* ldst) {
  __builtin_amdgcn_global_load_lds(
      (const __attribute__((address_space(1))) void*)gsrc,
      (__attribute__((address_space(3))) void*)ldst, 16, 0, 0);
}

// Tile 64ch x 128pos staged via global_load_lds (37 wave-insts per block, no
// VGPR round trip, no per-wave VMEM queue pressure). Consume: ch-pair per
// thread from LDS, packed sweep identical to R7.
__global__ __launch_bounds__(256)
__attribute__((amdgpu_waves_per_eu(4)))
void wlm_k1(
    const float* __restrict__ x,
    const float* __restrict__ la_, const float* __restrict__ ld_,
    const float* __restrict__ lg_, const float* __restrict__ th_,
    const float* __restrict__ bl_, float* __restrict__ y) {
  __shared__ float xs[TILE_P][64];   // 37,888 B -> 4 blocks/CU

  const int tid  = threadIdx.x;
  const int lane = tid & 63;
  const int wave = tid >> 6;
  const int s0 = blockIdx.x * SC;
  const int e0 = blockIdx.y * 64;
  const int b  = blockIdx.z;
  const size_t rowb = (size_t)b * T_SEQ;

  // ---- stage: 37 row-groups of 4 pos-rows; lane l -> (pos=rg*4+l/16,
  //      ch=(l&15)*4), LDS dest linear (base + lane*16) ----
  {
    const int ch4  = (lane & 15) * 4;
    const int psub = lane >> 4;
#pragma unroll
    for (int it = 0; it < 10; ++it) {
      const int rg = wave + it * 4;
      if (rg < TILE_P / 4) {
        const int pos = rg * 4 + psub;
        int g = s0 - 10 + pos;
        g = (g < 0) ? -g : g;
        g = (g >= T_SEQ) ? (2 * T_SEQ - 2 - g) : g;
        gload_lds16(&x[(rowb + g) * E_DIM + e0 + ch4], &xs[rg * 4][0]);
      }
    }
  }

  // ---- per-channel-pair params (c = ch-pair, pg = position group) ----
  const int c  = tid & 31;       // channel pair index
  const int pg = tid >> 5;       // 0..7, 16 positions each
  const int e  = e0 + 2 * c;
  const v2f la = *reinterpret_cast<const v2f*>(&la_[e]);
  const v2f ld = *reinterpret_cast<const v2f*>(&ld_[e]);
  const v2f lg = *reinterpret_cast<const v2f*>(&lg_[e]);
  const v2f th = *reinterpret_cast<const v2f*>(&th_[e]);
  v2f g2;
  g2.x = (fmaxf(lg.x, 0.f) + log1pf(expf(-fabsf(lg.x))) + 1e-6f) * cosf(th.x);
  g2.y = (fmaxf(lg.y, 0.f) + log1pf(expf(-fabsf(lg.y))) + 1e-6f) * cosf(th.y);

  const float b0 = bl_[0], b1 = bl_[1], b2 = bl_[2], b3 = bl_[3];
  const float mx = fmaxf(fmaxf(b0, b1), fmaxf(b2, b3));
  const float w0 = expf(b0 - mx), w1 = expf(b1 - mx),
              w2 = expf(b2 - mx), w3 = expf(b3 - mx);
  const float wr = 1.f / (w0 + w1 + w2 + w3);
  const v2f gw0 = g2 * sv(w0 * wr), gw1 = g2 * sv(w1 * wr),
            gw2 = g2 * sv(w2 * wr), gw3 = g2 * sv(w3 * wr);

  __syncthreads();   // drains the global_load_lds queue

  // ---- window from LDS: x_ref[sA-10 .. sA+25] for channel pair ----
  v2f xw[36];
#pragma unroll
  for (int i = 0; i < 36; ++i) {
    xw[i] = *reinterpret_cast<const v2f*>(&xs[pg * 16 + i][2 * c]);  // ds_read_b64
  }

  v2f acc[16];
#pragma unroll
  for (int j = 0; j < 16; ++j) acc[j] = v2f{0.f, 0.f};

  sweep<0>(xw, acc, la, ld, gw0, gw1, gw2, gw3);

  // ---- store (residual folded in during sweep) ----
  const int sA = s0 + pg * 16;
#pragma unroll
  for (int j = 0; j < 16; ++j) {
    *reinterpret_cast<v2f*>(&y[(rowb + sA + j) * E_DIM + e]) = acc[j];
  }
}

__global__ __launch_bounds__(256) void wlm_k2(float* __restrict__ y,
                                              const float* __restrict__ w,
                                              const float* __restrict__ bias) {
  const int token = blockIdx.x;
  const int tid = threadIdx.x;
  float* row = y + (size_t)token * E_DIM;

  float4 v = *reinterpret_cast<const float4*>(&row[tid * 4]);
  float s  = v.x + v.y + v.z + v.w;
  float sq = v.x * v.x + v.y * v.y + v.z * v.z + v.w * v.w;
#pragma unroll
  for (int off = 32; off; off >>= 1) {
    s  += __shfl_down(s, off);
    sq += __shfl_down(sq, off);
  }
  __shared__ float ps[4], pq[4], stat[2];
  const int wave = tid >> 6, lane = tid & 63;
  if (lane == 0) { ps[wave] = s; pq[wave] = sq; }
  __syncthreads();
  if (tid == 0) {
    const float S1 = ps[0] + ps[1] + ps[2] + ps[3];
    const float S2 = pq[0] + pq[1] + pq[2] + pq[3];
    const float mu = S1 * (1.f / E_DIM);
    const float var = S2 * (1.f / E_DIM) - mu * mu;
    stat[0] = mu;
    stat[1] = rsqrtf(var + 1e-5f);
  }
  __syncthreads();
  const float mu = stat[0], rstd = stat[1];
  const float4 wv = *reinterpret_cast<const float4*>(&w[tid * 4]);
  const float4 bv = *reinterpret_cast<const float4*>(&bias[tid * 4]);
  float4 o;
  o.x = (v.x - mu) * rstd * wv.x + bv.x;
  o.y = (v.y - mu) * rstd * wv.y + bv.y;
  o.z = (v.z - mu) * rstd * wv.z + bv.z;
  o.w = (v.w - mu) * rstd * wv.w + bv.w;
  *reinterpret_cast<float4*>(&row[tid * 4]) = o;
}

extern "C" void kernel_launch(void* const* d_in, const int* in_sizes, int n_in,
                              void* d_out, int out_size, void* d_ws, size_t ws_size,
                              hipStream_t stream) {
  const float* x   = (const float*)d_in[0];
  const float* la  = (const float*)d_in[1];
  const float* ldt = (const float*)d_in[2];
  const float* lg  = (const float*)d_in[3];
  const float* th  = (const float*)d_in[4];
  const float* bl  = (const float*)d_in[5];
  const float* lnw = (const float*)d_in[6];
  const float* lnb = (const float*)d_in[7];
  float* out = (float*)d_out;

  dim3 g1(T_SEQ / SC, E_DIM / 64, N_B);  // (32, 16, 8)
  wlm_k1<<<g1, 256, 0, stream>>>(x, la, ldt, lg, th, bl, out);
  wlm_k2<<<dim3(N_B * T_SEQ), 256, 0, stream>>>(out, lnw, lnb);
}